// Round 15
// baseline (2333.472 us; speedup 1.0000x reference)
//
#include <hip/hip_runtime.h>
#include <hip/hip_bf16.h>

// Precision policy (R3): pre-VQ math precise (expm1f/exact div); post-VQ fast.
// launch_bounds model (R5/R7/R8): hint w => VGPR budget ~512/(2w); below the
// live-range floor it SPILLS. Fused kernel: (256,3) => ~84 budget >= both
// paths' floors (fine 52, attco 68). R15: single kernel; per-batch 7th
// finisher continues into the coarse pipeline (device-scope atomic
// release/acquire; b-consecutive grid so batches complete early).
#define WSYNC() __builtin_amdgcn_wave_barrier()
__device__ __forceinline__ float frcp(float x){ return __builtin_amdgcn_rcpf(x); }
__device__ __forceinline__ float eluf_p(float x){ return x > 0.f ? x : expm1f(x); }           // pre-VQ
__device__ __forceinline__ float eluf_f(float x){ return x > 0.f ? x : __expf(x)-1.f; }       // post-VQ
__device__ __forceinline__ float seluf(float x){
  return x > 0.f ? 1.0507009873554805f*x : 1.7580993408473766f*(__expf(x)-1.f);               // post-VQ
}
__device__ __forceinline__ float sigm(float x){ return frcp(1.f+__expf(-x)); }                 // post-VQ

// ---------------- CBAM for C=32 rows, runtime D (20 or 50), in-place on X ----
__device__ __forceinline__ void cbam32(float* X, int D,
    const float* w1 /*[32][8]*/, const float* w2 /*[8][32]*/, const float* cv /*[14]*/,
    float* avgv, float* mxv, float* cav, float* smean, float* smax, float* sav,
    float* h1, float* h2, int tid)
{
  if (tid < 32){
    float s=0.f, m=-INFINITY;
    const float* row = X + tid*D;
    for (int d=0; d<D; ++d){ float v=row[d]; s+=v; m=fmaxf(m,v); }
    avgv[tid]=s/(float)D; mxv[tid]=m;
  }
  WSYNC();
  if (tid < 8){
    float a=0.f, mm=0.f;
    for (int c=0;c<32;++c){ a += avgv[c]*w1[c*8+tid]; mm += mxv[c]*w1[c*8+tid]; }
    h1[tid]=fmaxf(a,0.f); h2[tid]=fmaxf(mm,0.f);
  }
  WSYNC();
  if (tid < 32){
    float a=0.f;
    for (int j=0;j<8;++j) a += (h1[j]+h2[j])*w2[j*32+tid];
    cav[tid]=sigm(a);
  }
  __syncthreads();
  for (int o=tid;o<32*D;o+=256) X[o] *= cav[o/D];
  __syncthreads();
  if (tid < D){
    float s=0.f, m=-INFINITY;
    for (int c=0;c<32;++c){ float v=X[c*D+tid]; s+=v; m=fmaxf(m,v); }
    smean[tid]=s/32.f; smax[tid]=m;
  }
  WSYNC();
  if (tid < D){
    float a=0.f;
    for (int t=0;t<7;++t){
      int dd=tid+t-3;
      if (dd>=0 && dd<D) a += cv[t]*smean[dd] + cv[7+t]*smax[dd];
    }
    sav[tid]=a;
  }
  __syncthreads();
  for (int o=tid;o<32*D;o+=256) X[o] *= sigm(sav[o%D]);
  __syncthreads();
}

// ---------------- LDS unions --------------------------------------------------
struct FineSh {
  float uA[2928];
  float sf[32][5];
  float qm[5][5];
  float sw1[5][2];
  float sw2[2][5];
  float w1g[5][15];
  float w2g[20][30];
  float c1w1[32][8]; float c1w2[8][32]; float c1cv[14];
  float c2w1[32][8]; float c2w2[8][32]; float c2cv[14];
  float o_[32][5];
  float oqS[32][5];
  int   idxv[160];
  float gse[5];
  float wredS[5];
  float adjFT[32][32];
  float xw[32][30];
  float avgv[32], mxv[32], cav[32];
  float smean[50], smax[50], sav[50];
  float h1s[8], h2s[8];
  float ssew[4];
};
struct AttcoSh {
  float uB[2368];        // zeG[64][36]@0, vvG@2304; x1/x2 overlay post-VQ
  float xc[7][50];
  float pm[7][7];
  float o_[7][50];
  float oqS[7][50];
  float adjZ[50][7][7];
  float winS[7][32];
  float woutS[32][7];
  float cbS[128][33];    // att M_/S_/T_/attS_/aw_ overlay pre-stage
  float decC[128][8];
  int   idxv[350];
  float s_se[50], hh[25], gse[50];
  float adjA[49];
  float adjco[7][7];
  float cw1a[7], cw2a[7], cva[14], cw1b[7], cw2b[7], cvb[14];
  float avgv[7], mxv[7], cav[7], smean[60], smax[60], sav[60];
  float hsum[1];
  float ssew[4];
};
union ShU { FineSh f; AttcoSh a; };

#define TH(e,c)   uA[(e)*160+(c)]
#define CBS(c,e)  uA[800+(c)*16+(e)]
#define CBN(c)    uA[1312+(c)]
#define WINS(m,e) uA[1344+(m)*16+(e)]
#define WSUM(e)   uA[1856+(e)]
#define DECF(c,m) uA[1872+(c)*33+(m)]

__global__ __launch_bounds__(256, 3)
void k_all(const float* __restrict__ x, const float* __restrict__ ga_p, const float* __restrict__ ga_bias,
           const float* __restrict__ ga_q, const float* __restrict__ ga_theta,
           const float* __restrict__ ga_se_w1, const float* __restrict__ ga_se_w2,
           const float* __restrict__ ga_cb, const float* __restrict__ ga_win, const float* __restrict__ ga_wout,
           const float* __restrict__ rg_w1, const float* __restrict__ rg_w2,
           const float* __restrict__ cb1_w1, const float* __restrict__ cb1_w2, const float* __restrict__ cb1_cv,
           const float* __restrict__ cb2_w1, const float* __restrict__ cb2_w2, const float* __restrict__ cb2_cv,
           const float* __restrict__ Watt,
           const float* __restrict__ co_p, const float* __restrict__ co_bias,
           const float* __restrict__ co_q, const float* __restrict__ co_theta,
           const float* __restrict__ co_sew1, const float* __restrict__ co_sew2,
           const float* __restrict__ co_cb, const float* __restrict__ co_win, const float* __restrict__ co_wout,
           const float* __restrict__ co_w1, const float* __restrict__ co_w2,
           const float* __restrict__ cc1w1, const float* __restrict__ cc1w2, const float* __restrict__ cc1cv,
           const float* __restrict__ cc2w1, const float* __restrict__ cc2w2, const float* __restrict__ cc2cv,
           float* __restrict__ xr, float* __restrict__ outp, float* __restrict__ lossAcc,
           int* __restrict__ bcnt, int* __restrict__ doneCnt)
{
  const int tid = threadIdx.x;
  const int blk = blockIdx.x;
  const int b = blk / 7;         // b-consecutive: 7 k-blocks of a batch adjacent
  const int k = blk % 7;

  __shared__ ShU SH;
  __shared__ int contFlag;

  // ======================= FINE SECTION =====================================
  {
    float* uA = SH.f.uA;
    auto& sf = SH.f.sf;   auto& qm = SH.f.qm;   auto& sw1 = SH.f.sw1; auto& sw2 = SH.f.sw2;
    auto& w1g = SH.f.w1g; auto& w2g = SH.f.w2g;
    auto& c1w1 = SH.f.c1w1; auto& c1w2 = SH.f.c1w2; auto& c1cv = SH.f.c1cv;
    auto& c2w1 = SH.f.c2w1; auto& c2w2 = SH.f.c2w2; auto& c2cv = SH.f.c2cv;
    auto& o_ = SH.f.o_;   auto& oqS = SH.f.oqS;  auto& idxv = SH.f.idxv;
    auto& gse = SH.f.gse; auto& wredS = SH.f.wredS;
    auto& adjFT = SH.f.adjFT; auto& xw = SH.f.xw;
    auto& avgv = SH.f.avgv; auto& mxv = SH.f.mxv; auto& cav = SH.f.cav;
    auto& smean = SH.f.smean; auto& smax = SH.f.smax; auto& sav = SH.f.sav;
    auto& h1s = SH.f.h1s; auto& h2s = SH.f.h2s; auto& ssew = SH.f.ssew;

    // ---- stage weights/input ----
    {
      const float* xs = x + (size_t)(b*224 + k*32)*5;
      for (int i = tid; i < 160; i += 256) ((float*)sf)[i]    = xs[i];
      for (int i = tid; i < 25;  i += 256) ((float*)qm)[i]    = ga_q[k*25 + i];
      for (int i = tid; i < 800; i += 256) uA[i]              = ga_theta[k*800 + i];   // TH
      for (int i = tid; i < 10;  i += 256) ((float*)sw1)[i]   = ga_se_w1[k*10 + i];
      for (int i = tid; i < 10;  i += 256) ((float*)sw2)[i]   = ga_se_w2[k*10 + i];
      for (int i = tid; i < 512; i += 256) uA[800+i]          = ga_cb[k*512 + i];      // CBS
      for (int i = tid; i < 512; i += 256) uA[1344+i]         = ga_win[k*512 + i];     // WINS
      for (int i = tid; i < 75;  i += 256) ((float*)w1g)[i]   = rg_w1[k*75 + i];
      for (int i = tid; i < 600; i += 256) ((float*)w2g)[i]   = rg_w2[k*600 + i];
      for (int i = tid; i < 256; i += 256) ((float*)c1w1)[i]  = cb1_w1[k*256 + i];
      for (int i = tid; i < 256; i += 256) ((float*)c1w2)[i]  = cb1_w2[k*256 + i];
      for (int i = tid; i < 14;  i += 256) c1cv[i]            = cb1_cv[k*14 + i];
      for (int i = tid; i < 256; i += 256) ((float*)c2w1)[i]  = cb2_w1[k*256 + i];
      for (int i = tid; i < 256; i += 256) ((float*)c2w2)[i]  = cb2_w2[k*256 + i];
      for (int i = tid; i < 14;  i += 256) c2cv[i]            = cb2_cv[k*14 + i];
    }
    __syncthreads();

    if (tid < 160){
      int i = tid/5, d = tid%5;
      const float* pk = ga_p + k*1024 + i*32;
      float a = ga_bias[k*160 + tid];
      for (int j=0;j<32;++j) a += pk[j] * sf[j][d];
      o_[i][d] = a;
    } else if (tid < 176){
      int e = tid - 160;
      const float* wg = ga_wout + k*512 + e*32;
      float s = 0.f;
      #pragma unroll
      for (int m=0;m<32;++m) s += wg[m];
      WSUM(e) = s;
    } else if (tid >= 224){
      int c = tid - 224;
      float s = 0.f;
      #pragma unroll
      for (int e=0;e<16;++e){ float v = CBS(c,e); s += v*v; }
      CBN(c) = s;
    }
    __syncthreads();
    if (tid < 160){
      int i = tid/5, e = tid%5;
      float a = 0.f;
      #pragma unroll
      for (int d=0;d<5;++d) a += o_[i][d]*qm[d][e];
      oqS[i][e] = a;
    }
    __syncthreads();

    // ---- fused VQ (tid<160) precise; spares: xw and dec table
    float sse = 0.f;
    if (tid < 160){
      const int f = tid >> 5, i = tid & 31;
      const float oq0=oqS[i][0], oq1=oqS[i][1], oq2=oqS[i][2], oq3=oqS[i][3], oq4=oqS[i][4];
      float v[16];
      #pragma unroll
      for (int e=0;e<16;++e) v[e] = 0.f;
      float s1 = 0.f;
      #pragma unroll 4
      for (int m=0;m<32;++m){
        const int c = m*5+f;
        float a = oq0*TH(0,c) + oq1*TH(1,c) + oq2*TH(2,c) + oq3*TH(3,c) + oq4*TH(4,c);
        a = eluf_p(a);
        s1 += fabsf(a);
        #pragma unroll
        for (int e=0;e<16;++e) v[e] += a*WINS(m,e);
      }
      const float inv = 1.f/(s1 + 1e-6f);
      #pragma unroll
      for (int e=0;e<16;++e) v[e] *= inv;
      float vv = 0.f;
      #pragma unroll
      for (int e=0;e<16;++e) vv += v[e]*v[e];
      float best = 3.4e38f; int bi = 0;
      #pragma unroll 4
      for (int c=0;c<32;++c){
        float d = 0.f;
        #pragma unroll
        for (int e=0;e<16;++e) d += v[e]*CBS(c,e);
        float d2 = vv - 2.f*d + CBN(c);
        if (d2 < best){ best = d2; bi = c; }
      }
      idxv[tid] = bi;
      sse = best;
    } else {
      for (int o = tid-160; o < 480; o += 96){
        int j = o/15, c = o%15;
        float a = 0.f;
        #pragma unroll
        for (int d=0;d<5;++d) a += sf[j][d]*w1g[d][c];
        xw[j][c] = a;
      }
      const float* wg = ga_wout + k*512;
      for (int o = tid-160; o < 1024; o += 96){
        int c = o >> 5, m = o & 31;
        float a = 0.f;
        #pragma unroll
        for (int e=0;e<16;++e) a += CBS(c,e)*wg[e*32+m];
        DECF(c,m) = a;
      }
    }
    __syncthreads();

    // ---- SE partial
    {
      float sep = 0.f;
      if (tid < 160){
        const int id = idxv[tid];
        #pragma unroll
        for (int e=0;e<16;++e) sep += CBS(id,e)*WSUM(e);
      }
      #pragma unroll
      for (int off=16; off>=1; off>>=1) sep += __shfl_xor(sep, off);
      if (tid < 160 && (tid&31)==0) wredS[tid>>5] = sep;
    }
    __syncthreads();
    if (tid == 0){
      float h0=0.f, h1=0.f;
      #pragma unroll
      for (int f=0; f<5; ++f){
        float s = wredS[f] * (1.f/1024.f);
        h0 += s*sw1[f][0]; h1 += s*sw1[f][1];
      }
      h0 = fmaxf(h0,0.f); h1 = fmaxf(h1,0.f);
      #pragma unroll
      for (int f=0; f<5; ++f) gse[f] = sigm(h0*sw2[0][f] + h1*sw2[1][f]);
    }
    __syncthreads();

    // ---- combine
    for (int o = tid; o < 1024; o += 256){
      int i = o & 31, m = o >> 5;
      float a = 0.f;
      #pragma unroll
      for (int f=0; f<5; ++f)
        a += eluf_f(DECF(idxv[(f<<5)|i], m)*(1.f+gse[f]));
      adjFT[m][i] = eluf_f(a);
    }
    __syncthreads();
    if (tid < 32){
      float s = 0.f;
      #pragma unroll
      for (int m=0;m<32;++m) s += fabsf(adjFT[m][tid]);
      float inv = 1.f/(s + 1e-6f);
      #pragma unroll
      for (int m=0;m<32;++m) adjFT[m][tid] *= inv;
    }
    __syncthreads();

    // ---- res_gcn layer 1; x1c overlays dead th region
    float* x1c = uA;   // [32][20]
    for (int o = tid; o < 480; o += 256){
      int i = o/15, c = o%15;
      float a = 0.f;
      for (int j=0;j<32;++j) a += adjFT[j][i]*xw[j][c];
      x1c[i*20 + 5+c] = seluf(a);
    }
    for (int o = tid; o < 160; o += 256) x1c[(o/5)*20 + o%5] = ((const float*)sf)[o];
    __syncthreads();
    cbam32(x1c, 20, &c1w1[0][0], &c1w2[0][0], c1cv,
           avgv, mxv, cav, smean, smax, sav, h1s, h2s, tid);

    // ---- res_gcn layer 2; cat2 overlays dead cbS/winS/dec region
    float* cat2 = uA + 640; // [32][50]
    for (int o = tid; o < 960; o += 256){
      int j = o/30, c = o%30;
      float a = 0.f;
      #pragma unroll
      for (int d=0;d<20;++d) a += x1c[j*20+d]*w2g[d][c];
      xw[j][c] = a;
    }
    __syncthreads();
    for (int o = tid; o < 960; o += 256){
      int i = o/30, c = o%30;
      float a = 0.f;
      for (int j=0;j<32;++j) a += adjFT[j][i]*xw[j][c];
      cat2[i*50 + 20+c] = seluf(a);
    }
    for (int o = tid; o < 640; o += 256) cat2[(o/20)*50 + o%20] = x1c[o];
    __syncthreads();
    cbam32(cat2, 50, &c2w1[0][0], &c2w2[0][0], c2cv,
           avgv, mxv, cav, smean, smax, sav, h1s, h2s, tid);

    // ---- write xi = elu(out), layout [b][k][32][50]
    {
      float* dst = xr + (size_t)(b*7 + k)*1600;
      for (int o = tid; o < 1600; o += 256) dst[o] = eluf_f(cat2[o]);
    }

    // ---- loss partials
    {
      float p = sse;
      for (int off=32; off>=1; off>>=1) p += __shfl_down(p, off);
      if ((tid & 63) == 0) ssew[tid>>6] = p;
    }
    __threadfence();          // each thread: flush own xr stores device-wide
    __syncthreads();          // all fences complete before release atomic
    if (tid == 0){
      atomicAdd(lossAcc, (ssew[0]+ssew[1]+ssew[2]+ssew[3]) * (1.25f/2621440.f));
      __threadfence();
      int prev = atomicAdd(&bcnt[b], 1);    // release; 7th finisher continues
      contFlag = (prev == 6) ? 1 : 0;
    }
    __syncthreads();
  }
  if (!contFlag) return;

  // ======================= ATTCO SECTION (7th finisher, 256 threads) ========
  {
    const int lane = tid & 63, wid = tid >> 6;   // wid 0..3
    float* uB = SH.a.uB;
    auto& xc = SH.a.xc; auto& pm = SH.a.pm; auto& o_ = SH.a.o_; auto& oqS = SH.a.oqS;
    auto& adjZ = SH.a.adjZ; auto& winS = SH.a.winS; auto& woutS = SH.a.woutS;
    auto& cbS = SH.a.cbS; auto& decC = SH.a.decC; auto& idxv = SH.a.idxv;
    auto& s_se = SH.a.s_se; auto& hh = SH.a.hh; auto& gse = SH.a.gse;
    auto& adjA = SH.a.adjA; auto& adjco = SH.a.adjco;
    auto& cw1a = SH.a.cw1a; auto& cw2a = SH.a.cw2a; auto& cva = SH.a.cva;
    auto& cw1b = SH.a.cw1b; auto& cw2b = SH.a.cw2b; auto& cvb = SH.a.cvb;
    auto& avgv = SH.a.avgv; auto& mxv = SH.a.mxv; auto& cav = SH.a.cav;
    auto& smean = SH.a.smean; auto& smax = SH.a.smax; auto& sav = SH.a.sav;
    auto& hsum = SH.a.hsum; auto& ssew = SH.a.ssew;

    float* attU  = &cbS[0][0];
    float* M_    = attU;        // [7][50]
    float* S_    = attU + 350;  // [7][80]
    float* T_    = attU + 910;  // [7][50]
    float* attS_ = attU + 1260; // [7][32]
    float* aw_   = attU + 1484; // [7][32]

    // stage small consts
    for (int i = tid; i < 49;   i += 256) ((float*)pm)[i]    = co_p[i];
    for (int i = tid; i < 224;  i += 256) ((float*)winS)[i]  = co_win[i];
    for (int i = tid; i < 224;  i += 256) ((float*)woutS)[i] = co_wout[i];
    if (tid < 7)                       cw1a[tid]     = cc1w1[tid];
    else if (tid >= 32 && tid < 39)    cw2a[tid-32]  = cc1w2[tid-32];
    else if (tid >= 64 && tid < 78)    cva[tid-64]   = cc1cv[tid-64];
    else if (tid >= 96 && tid < 103)   cw1b[tid-96]  = cc2w1[tid-96];
    else if (tid >= 128 && tid < 135)  cw2b[tid-128] = cc2w2[tid-128];
    else if (tid >= 160 && tid < 174)  cvb[tid-160]  = cc2cv[tid-160];

    // ---- attention coarsening
    const float* src = xr + (size_t)b*11200;
    for (int o = tid; o < 350; o += 256){
      int kk = o/50, d = o%50;
      float s = 0.f;
      const float* p = src + kk*1600 + d;
      for (int n=0;n<32;++n) s += p[n*50];
      M_[kk*50+d] = s;
    }
    __syncthreads();
    for (int o = tid; o < 560; o += 256){
      int kk = o/80, h = o%80;
      float s = 0.f;
      #pragma unroll 8
      for (int d=0;d<50;++d) s += M_[kk*50+d]*Watt[d*80+h];
      S_[kk*80+h] = s;
    }
    __syncthreads();
    for (int o = tid; o < 350; o += 256){
      int kk = o/50, d = o%50;
      float s = 0.f;
      const float* wr = Watt + d*80;
      #pragma unroll 8
      for (int h=0;h<80;++h) s += S_[kk*80+h]*wr[h];
      T_[kk*50+d] = s;
    }
    __syncthreads();
    for (int o = tid; o < 224; o += 256){
      int kk = o >> 5, n = o & 31;
      float s = 0.f;
      const float* p = src + kk*1600 + n*50;
      #pragma unroll 8
      for (int d=0;d<50;++d) s += p[d]*T_[kk*50+d];
      attS_[kk*32+n] = s;
    }
    __syncthreads();
    if (tid < 7){
      float m = -INFINITY;
      for (int n=0;n<32;++n) m = fmaxf(m, attS_[tid*32+n]);
      float s = 0.f;
      for (int n=0;n<32;++n){ float e = expf(attS_[tid*32+n]-m); aw_[tid*32+n] = e; s += e; }
      for (int n=0;n<32;++n) aw_[tid*32+n] = aw_[tid*32+n]/s;
    }
    __syncthreads();
    for (int o = tid; o < 350; o += 256){
      int kk = o/50, d = o%50;
      float s = 0.f;
      const float* p = src + kk*1600 + d;
      for (int n=0;n<32;++n) s += aw_[kk*32+n]*p[n*50];
      xc[kk][d] = s;
    }
    __syncthreads();   // att buffers dead; cbS region reusable

    // ---- coarse pipeline
    for (int i = tid; i < 4096; i += 256) cbS[i>>5][i&31] = co_cb[i];
    for (int o = tid; o < 350; o += 256){
      int i = o/50, d = o%50;
      float a = co_bias[o];
      #pragma unroll
      for (int j=0;j<7;++j) a += pm[i][j]*xc[j][d];
      o_[i][d] = a;
    }
    __syncthreads();
    for (int o = tid; o < 350; o += 256){
      int i = o/50, e = o%50;
      float a = 0.f;
      #pragma unroll 8
      for (int d=0;d<50;++d) a += o_[i][d]*co_q[d*50+e];
      oqS[i][e] = a;
    }
    __syncthreads();
    for (int c = tid; c < 350; c += 256){
      float acc[7] = {0,0,0,0,0,0,0};
      #pragma unroll 5
      for (int e=0;e<50;++e){
        float t = co_theta[e*350+c];
        #pragma unroll
        for (int i=0;i<7;++i) acc[i] += oqS[i][e]*t;
      }
      int f = c % 50, n2 = c / 50;
      #pragma unroll
      for (int i=0;i<7;++i) adjZ[f][i][n2] = eluf_p(acc[i]);
    }
    __syncthreads();
    for (int o = tid; o < 350; o += 256){
      float* rowp = &adjZ[0][0][0] + o*7;
      float s = 0.f;
      #pragma unroll
      for (int m=0;m<7;++m) s += fabsf(rowp[m]);
      float den = s + 1e-6f;
      #pragma unroll
      for (int m=0;m<7;++m) rowp[m] /= den;
    }
    __syncthreads();

    // ---- VQ: 2 codes/lane from LDS, 4 waves -> v += 4
    float c0[32], c1[32];
    #pragma unroll
    for (int e=0;e<32;++e){ c0[e] = cbS[lane][e]; c1[e] = cbS[lane+64][e]; }
    float cn0 = 0.f, cn1 = 0.f;
    #pragma unroll
    for (int e=0;e<32;++e){ cn0 += c0[e]*c0[e]; cn1 += c1[e]*c1[e]; }
    float* zeG = uB;            // [64][36]
    float* vvG = uB + 2304;     // [64]
    float sse = 0.f;
    for (int g0 = 0; g0 < 350; g0 += 64){
      int nv = (350 - g0 < 64) ? (350 - g0) : 64;
      for (int o = tid; o < nv*32; o += 256){
        int v = o >> 5, e = o & 31;
        const float* rowp = &adjZ[0][0][0] + (g0+v)*7;
        float a = 0.f;
        #pragma unroll
        for (int m=0;m<7;++m) a += rowp[m]*winS[m][e];
        zeG[v*36+e] = a;
      }
      __syncthreads();
      if (tid < nv){
        float a = 0.f;
        #pragma unroll
        for (int e=0;e<32;++e){ float t = zeG[tid*36+e]; a += t*t; }
        vvG[tid] = a;
      }
      __syncthreads();
      for (int v = wid; v < nv; v += 4){
        float d0 = 0.f, d1 = 0.f;
        #pragma unroll
        for (int e=0;e<32;++e){
          float ve = zeG[v*36+e];
          d0 += ve*c0[e]; d1 += ve*c1[e];
        }
        float vv = vvG[v];
        float dist0 = vv - 2.f*d0 + cn0;
        float dist1 = vv - 2.f*d1 + cn1;
        float best = dist0; int bi = lane;
        if (dist1 < best){ best = dist1; bi = lane + 64; }
        for (int off = 32; off >= 1; off >>= 1){
          float ob = __shfl_xor(best, off);
          int oi   = __shfl_xor(bi, off);
          if (ob < best || (ob == best && oi < bi)){ best = ob; bi = oi; }
        }
        if (lane == 0){ idxv[g0+v] = bi; sse += best; }
      }
      __syncthreads();
    }

    // ---- decC + recon
    for (int o = tid; o < 896; o += 256){
      int c = o / 7, m = o % 7;
      float a = 0.f;
      #pragma unroll
      for (int e=0;e<32;++e) a += cbS[c][e]*woutS[e][m];
      decC[c][m] = a;
    }
    __syncthreads();
    for (int o = tid; o < 2450; o += 256){
      int fr = o / 49, r = o % 49, i = r / 7, m = r % 7;
      (&adjZ[0][0][0])[o] = decC[idxv[fr*7 + i]][m];
    }
    __syncthreads();
    const float* reconC = &adjZ[0][0][0];

    // ---- SE chain (wave-0-local)
    if (tid < 50){
      float s = 0.f;
      for (int r=0;r<49;++r) s += reconC[tid*49 + r];
      s_se[tid] = s / 49.f;
    }
    WSYNC();
    if (tid < 25){
      float a = 0.f;
      #pragma unroll 8
      for (int f=0;f<50;++f) a += s_se[f]*co_sew1[f*25+tid];
      hh[tid] = fmaxf(a, 0.f);
    }
    WSYNC();
    if (tid < 50){
      float a = 0.f;
      #pragma unroll 8
      for (int t2=0;t2<25;++t2) a += hh[t2]*co_sew2[t2*50+tid];
      gse[tid] = sigm(a);
    }
    WSYNC();
    if (tid < 49){
      float a = 0.f;
      for (int f=0;f<50;++f) a += eluf_f(reconC[f*49+tid]*(1.f+gse[f]));
      adjA[tid] = eluf_f(a);
    }
    WSYNC();
    if (tid < 7){
      float s = 0.f;
      #pragma unroll
      for (int m=0;m<7;++m) s += fabsf(adjA[tid*7+m]);
      float den = s + 1e-6f;
      #pragma unroll
      for (int m=0;m<7;++m) adjco[tid][m] = adjA[tid*7+m]/den;
    }
    __syncthreads();

    // ---- res_gcn2 layer 1 (overlay dead zeG)
    float* x1w = uB;           // [7][55]
    float* x1s = uB + 385;
    float* x1b = uB + 770;
    float* xw2 = uB + 1155;    // [7][60]
    float* x2s = uB + 1575;
    for (int o = tid; o < 385; o += 256){
      int j = o/55, c = o%55;
      float a = 0.f;
      #pragma unroll 8
      for (int d=0;d<50;++d) a += xc[j][d]*co_w1[d*55+c];
      x1w[o] = a;
    }
    __syncthreads();
    for (int o = tid; o < 385; o += 256){
      int i = o/55, c = o%55;
      float a = 0.f;
      #pragma unroll
      for (int j=0;j<7;++j) a += adjco[i][j]*x1w[j*55+c];
      x1s[o] = seluf(a);
    }
    __syncthreads();
    if (tid < 7){
      float s=0.f, m=-INFINITY;
      for (int d=0;d<55;++d){ float v = x1s[tid*55+d]; s += v; m = fmaxf(m,v); }
      avgv[tid] = s/55.f; mxv[tid] = m;
    }
    WSYNC();
    if (tid == 0){
      float ha=0.f, hm=0.f;
      #pragma unroll
      for (int c=0;c<7;++c){ ha += avgv[c]*cw1a[c]; hm += mxv[c]*cw1a[c]; }
      hsum[0] = fmaxf(ha,0.f) + fmaxf(hm,0.f);
    }
    WSYNC();
    if (tid < 7) cav[tid] = sigm(hsum[0]*cw2a[tid]);
    __syncthreads();
    for (int o = tid; o < 385; o += 256) x1w[o] = x1s[o]*cav[o/55];
    __syncthreads();
    if (tid < 55){
      float s=0.f, m=-INFINITY;
      #pragma unroll
      for (int c=0;c<7;++c){ float v = x1w[c*55+tid]; s += v; m = fmaxf(m,v); }
      smean[tid] = s/7.f; smax[tid] = m;
    }
    WSYNC();
    if (tid < 55){
      float a = 0.f;
      #pragma unroll
      for (int t2=0;t2<7;++t2){
        int dd = tid + t2 - 3;
        if (dd >= 0 && dd < 55) a += cva[t2]*smean[dd] + cva[7+t2]*smax[dd];
      }
      sav[tid] = a;
    }
    __syncthreads();
    for (int o = tid; o < 385; o += 256)
      x1b[o] = x1w[o]*sigm(sav[o%55]) + x1s[o];
    __syncthreads();

    // ---- res_gcn2 layer 2
    for (int o = tid; o < 420; o += 256){
      int j = o/60, c = o%60;
      float a = 0.f;
      #pragma unroll 8
      for (int d=0;d<55;++d) a += x1b[j*55+d]*co_w2[d*60+c];
      xw2[o] = a;
    }
    __syncthreads();
    for (int o = tid; o < 420; o += 256){
      int i = o/60, c = o%60;
      float a = 0.f;
      #pragma unroll
      for (int j=0;j<7;++j) a += adjco[i][j]*xw2[j*60+c];
      x2s[o] = seluf(a);
    }
    __syncthreads();
    if (tid < 7){
      float s=0.f, m=-INFINITY;
      for (int d=0;d<60;++d){ float v = x2s[tid*60+d]; s += v; m = fmaxf(m,v); }
      avgv[tid] = s/60.f; mxv[tid] = m;
    }
    WSYNC();
    if (tid == 0){
      float ha=0.f, hm=0.f;
      #pragma unroll
      for (int c=0;c<7;++c){ ha += avgv[c]*cw1b[c]; hm += mxv[c]*cw1b[c]; }
      hsum[0] = fmaxf(ha,0.f) + fmaxf(hm,0.f);
    }
    WSYNC();
    if (tid < 7) cav[tid] = sigm(hsum[0]*cw2b[tid]);
    __syncthreads();
    for (int o = tid; o < 420; o += 256) xw2[o] = x2s[o]*cav[o/60];
    __syncthreads();
    if (tid < 60){
      float s=0.f, m=-INFINITY;
      #pragma unroll
      for (int c=0;c<7;++c){ float v = xw2[c*60+tid]; s += v; m = fmaxf(m,v); }
      smean[tid] = s/7.f; smax[tid] = m;
    }
    WSYNC();
    if (tid < 60){
      float a = 0.f;
      #pragma unroll
      for (int t2=0;t2<7;++t2){
        int dd = tid + t2 - 3;
        if (dd >= 0 && dd < 60) a += cvb[t2]*smean[dd] + cvb[7+t2]*smax[dd];
      }
      sav[tid] = a;
    }
    __syncthreads();
    for (int o = tid; o < 420; o += 256){
      float val = xw2[o]*sigm(sav[o%60]) + x2s[o];
      outp[1 + (size_t)b*420 + o] = val;
    }

    // ---- loss; last attco finisher emits outp[0]
    if (lane == 0) ssew[wid] = sse;
    __syncthreads();
    if (tid == 0){
      atomicAdd(lossAcc, (ssew[0]+ssew[1]+ssew[2]+ssew[3]) * (2.5f/11468800.f));
      __threadfence();
      int prev = atomicAdd(doneCnt, 1);
      if (prev == 1023){
        outp[0] = atomicAdd(lossAcc, 0.0f);
      }
    }
  }
}

extern "C" void kernel_launch(void* const* d_in, const int* in_sizes, int n_in,
                              void* d_out, int out_size, void* d_ws, size_t ws_size,
                              hipStream_t stream)
{
  const float* x          = (const float*)d_in[0];
  const float* ga_p       = (const float*)d_in[1];
  const float* ga_bias    = (const float*)d_in[2];
  const float* ga_q       = (const float*)d_in[3];
  const float* ga_theta   = (const float*)d_in[4];
  const float* ga_se_w1   = (const float*)d_in[5];
  const float* ga_se_w2   = (const float*)d_in[6];
  const float* ga_cb      = (const float*)d_in[7];
  const float* ga_win     = (const float*)d_in[8];
  const float* ga_wout    = (const float*)d_in[9];
  const float* rg_w1      = (const float*)d_in[10];
  const float* rg_w2      = (const float*)d_in[11];
  const float* cb1_w1     = (const float*)d_in[12];
  const float* cb1_w2     = (const float*)d_in[13];
  const float* cb1_conv   = (const float*)d_in[14];
  const float* cb2_w1     = (const float*)d_in[15];
  const float* cb2_w2     = (const float*)d_in[16];
  const float* cb2_conv   = (const float*)d_in[17];
  const float* co_p       = (const float*)d_in[18];
  const float* co_bias    = (const float*)d_in[19];
  const float* co_q       = (const float*)d_in[20];
  const float* co_theta   = (const float*)d_in[21];
  const float* co_se_w1   = (const float*)d_in[22];
  const float* co_se_w2   = (const float*)d_in[23];
  const float* co_cb      = (const float*)d_in[24];
  const float* co_win     = (const float*)d_in[25];
  const float* co_wout    = (const float*)d_in[26];
  const float* co_rg_w1   = (const float*)d_in[27];
  const float* co_rg_w2   = (const float*)d_in[28];
  const float* co_cb1_w1  = (const float*)d_in[29];
  const float* co_cb1_w2  = (const float*)d_in[30];
  const float* co_cb1_cv  = (const float*)d_in[31];
  const float* co_cb2_w1  = (const float*)d_in[32];
  const float* co_cb2_w2  = (const float*)d_in[33];
  const float* co_cb2_cv  = (const float*)d_in[34];
  const float* W_att      = (const float*)d_in[35];

  char* base = (char*)d_ws;
  float* lossAcc = (float*)base;                 // 4B @0
  int*   doneCnt = (int*)(base + 64);            // 4B @64
  int*   bcnt    = (int*)(base + 256);           // 1024 ints @256..4352
  float* xr  = (float*)(base + 8192);            // [1024][7][32][50] f32

  float* outp = (float*)d_out;

  hipMemsetAsync(d_ws, 0, 8192, stream);
  k_all<<<7168, 256, 0, stream>>>(x, ga_p, ga_bias, ga_q, ga_theta, ga_se_w1, ga_se_w2,
                                  ga_cb, ga_win, ga_wout, rg_w1, rg_w2,
                                  cb1_w1, cb1_w2, cb1_conv, cb2_w1, cb2_w2, cb2_conv,
                                  W_att,
                                  co_p, co_bias, co_q, co_theta, co_se_w1, co_se_w2,
                                  co_cb, co_win, co_wout, co_rg_w1, co_rg_w2,
                                  co_cb1_w1, co_cb1_w2, co_cb1_cv,
                                  co_cb2_w1, co_cb2_w2, co_cb2_cv,
                                  xr, outp, lossAcc, bcnt, doneCnt);
}

// Round 16
// 442.120 us; speedup vs baseline: 5.2779x; 5.2779x over previous
//
#include <hip/hip_runtime.h>
#include <hip/hip_bf16.h>

// Precision policy (R3): pre-VQ math precise (expm1f/exact div); post-VQ fast.
// launch_bounds (R5/R7/R8): waves-hint w => allocator budgets ~512/(2w) VGPR;
// below the live-range floor it SPILLS. k_attco gets NO hint.
// R15 lesson: fusing fine+attco into one kernel forced the 50KB LDS union on
// all blocks -> residency collapse + 5.5x bank conflicts -> 2333us. Two-kernel
// split with per-kernel LDS/occupancy tuning is strictly better. This is R14
// (best known: 442us).
#define WSYNC() __builtin_amdgcn_wave_barrier()
__device__ __forceinline__ float frcp(float x){ return __builtin_amdgcn_rcpf(x); }
__device__ __forceinline__ float eluf_p(float x){ return x > 0.f ? x : expm1f(x); }           // pre-VQ
__device__ __forceinline__ float eluf_f(float x){ return x > 0.f ? x : __expf(x)-1.f; }       // post-VQ
__device__ __forceinline__ float seluf(float x){
  return x > 0.f ? 1.0507009873554805f*x : 1.7580993408473766f*(__expf(x)-1.f);               // post-VQ
}
__device__ __forceinline__ float sigm(float x){ return frcp(1.f+__expf(-x)); }                 // post-VQ

// ---------------- CBAM for C=32 rows, runtime D (20 or 50), in-place on X ----
__device__ __forceinline__ void cbam32(float* X, int D,
    const float* w1 /*[32][8]*/, const float* w2 /*[8][32]*/, const float* cv /*[14]*/,
    float* avgv, float* mxv, float* cav, float* smean, float* smax, float* sav,
    float* h1, float* h2, int tid)
{
  if (tid < 32){
    float s=0.f, m=-INFINITY;
    const float* row = X + tid*D;
    for (int d=0; d<D; ++d){ float v=row[d]; s+=v; m=fmaxf(m,v); }
    avgv[tid]=s/(float)D; mxv[tid]=m;
  }
  WSYNC();
  if (tid < 8){
    float a=0.f, mm=0.f;
    for (int c=0;c<32;++c){ a += avgv[c]*w1[c*8+tid]; mm += mxv[c]*w1[c*8+tid]; }
    h1[tid]=fmaxf(a,0.f); h2[tid]=fmaxf(mm,0.f);
  }
  WSYNC();
  if (tid < 32){
    float a=0.f;
    for (int j=0;j<8;++j) a += (h1[j]+h2[j])*w2[j*32+tid];
    cav[tid]=sigm(a);
  }
  __syncthreads();
  for (int o=tid;o<32*D;o+=256) X[o] *= cav[o/D];
  __syncthreads();
  if (tid < D){
    float s=0.f, m=-INFINITY;
    for (int c=0;c<32;++c){ float v=X[c*D+tid]; s+=v; m=fmaxf(m,v); }
    smean[tid]=s/32.f; smax[tid]=m;
  }
  WSYNC();
  if (tid < D){
    float a=0.f;
    for (int t=0;t<7;++t){
      int dd=tid+t-3;
      if (dd>=0 && dd<D) a += cv[t]*smean[dd] + cv[7+t]*smax[dd];
    }
    sav[tid]=a;
  }
  __syncthreads();
  for (int o=tid;o<32*D;o+=256) X[o] *= sigm(sav[o%D]);
  __syncthreads();
}

// ---------------- Kernel 1: per (k,b) fine pipeline -------------------------
#define TH(e,c)   uA[(e)*160+(c)]
#define CBS(c,e)  uA[800+(c)*16+(e)]
#define CBN(c)    uA[1312+(c)]
#define WINS(m,e) uA[1344+(m)*16+(e)]
#define WSUM(e)   uA[1856+(e)]
#define DECF(c,m) uA[1872+(c)*33+(m)]
#define X1C_BASE  (uA)
#define CAT2_BASE (uA+640)

__global__ __launch_bounds__(256, 4)
void k_fine(const float* __restrict__ x, const float* __restrict__ ga_p, const float* __restrict__ ga_bias,
            const float* __restrict__ ga_q, const float* __restrict__ ga_theta,
            const float* __restrict__ ga_se_w1, const float* __restrict__ ga_se_w2,
            const float* __restrict__ ga_cb, const float* __restrict__ ga_win, const float* __restrict__ ga_wout,
            const float* __restrict__ rg_w1, const float* __restrict__ rg_w2,
            const float* __restrict__ cb1_w1, const float* __restrict__ cb1_w2, const float* __restrict__ cb1_cv,
            const float* __restrict__ cb2_w1, const float* __restrict__ cb2_w2, const float* __restrict__ cb2_cv,
            float* __restrict__ xr, float* __restrict__ lossAcc)
{
  const int tid = threadIdx.x;
  const int blk = blockIdx.x;
  const int k = blk >> 10;        // K major
  const int b = blk & 1023;

  __shared__ float uA[2928];
  __shared__ float sf[32][5];
  __shared__ float qm[5][5];
  __shared__ float sw1[5][2];
  __shared__ float sw2[2][5];
  __shared__ float w1g[5][15];
  __shared__ float w2g[20][30];
  __shared__ float c1w1[32][8]; __shared__ float c1w2[8][32]; __shared__ float c1cv[14];
  __shared__ float c2w1[32][8]; __shared__ float c2w2[8][32]; __shared__ float c2cv[14];
  __shared__ float o_[32][5];
  __shared__ float oqS[32][5];
  __shared__ int   idxv[160];
  __shared__ float gse[5];
  __shared__ float wredS[5];
  __shared__ float adjFT[32][32];     // adjFT[m][i] = adjacency[i][m]
  __shared__ float xw[32][30];
  __shared__ float avgv[32], mxv[32], cav[32];
  __shared__ float smean[50], smax[50], sav[50];
  __shared__ float h1s[8], h2s[8];
  __shared__ float ssew[4];

  // ---- stage weights/input ----
  {
    const float* xs = x + (size_t)(b*224 + k*32)*5;
    for (int i = tid; i < 160; i += 256) ((float*)sf)[i]    = xs[i];
    for (int i = tid; i < 25;  i += 256) ((float*)qm)[i]    = ga_q[k*25 + i];
    for (int i = tid; i < 800; i += 256) uA[i]              = ga_theta[k*800 + i];   // TH
    for (int i = tid; i < 10;  i += 256) ((float*)sw1)[i]   = ga_se_w1[k*10 + i];
    for (int i = tid; i < 10;  i += 256) ((float*)sw2)[i]   = ga_se_w2[k*10 + i];
    for (int i = tid; i < 512; i += 256) uA[800+i]          = ga_cb[k*512 + i];      // CBS
    for (int i = tid; i < 512; i += 256) uA[1344+i]         = ga_win[k*512 + i];     // WINS
    for (int i = tid; i < 75;  i += 256) ((float*)w1g)[i]   = rg_w1[k*75 + i];
    for (int i = tid; i < 600; i += 256) ((float*)w2g)[i]   = rg_w2[k*600 + i];
    for (int i = tid; i < 256; i += 256) ((float*)c1w1)[i]  = cb1_w1[k*256 + i];
    for (int i = tid; i < 256; i += 256) ((float*)c1w2)[i]  = cb1_w2[k*256 + i];
    for (int i = tid; i < 14;  i += 256) c1cv[i]            = cb1_cv[k*14 + i];
    for (int i = tid; i < 256; i += 256) ((float*)c2w1)[i]  = cb2_w1[k*256 + i];
    for (int i = tid; i < 256; i += 256) ((float*)c2w2)[i]  = cb2_w2[k*256 + i];
    for (int i = tid; i < 14;  i += 256) c2cv[i]            = cb2_cv[k*14 + i];
  }
  __syncthreads();

  // ---- o = p @ sf + bias (tid<160); wsum (160..175, global wout); cbn (224..)
  if (tid < 160){
    int i = tid/5, d = tid%5;
    const float* pk = ga_p + k*1024 + i*32;
    float a = ga_bias[k*160 + tid];
    for (int j=0;j<32;++j) a += pk[j] * sf[j][d];
    o_[i][d] = a;
  } else if (tid < 176){
    int e = tid - 160;
    const float* wg = ga_wout + k*512 + e*32;
    float s = 0.f;
    #pragma unroll
    for (int m=0;m<32;++m) s += wg[m];
    WSUM(e) = s;
  } else if (tid >= 224){
    int c = tid - 224;
    float s = 0.f;
    #pragma unroll
    for (int e=0;e<16;++e){ float v = CBS(c,e); s += v*v; }
    CBN(c) = s;
  }
  __syncthreads();
  if (tid < 160){
    int i = tid/5, e = tid%5;
    float a = 0.f;
    #pragma unroll
    for (int d=0;d<5;++d) a += o_[i][d]*qm[d][e];
    oqS[i][e] = a;
  }
  __syncthreads();

  // ---- fused VQ (tid<160): g -> L1 norm -> ze -> argmin (all precise)
  //      spare threads: xw = sf@w1g  and  dec[c][m] = cb[c]·wout[:,m]
  float sse = 0.f;
  if (tid < 160){
    const int f = tid >> 5, i = tid & 31;
    const float oq0=oqS[i][0], oq1=oqS[i][1], oq2=oqS[i][2], oq3=oqS[i][3], oq4=oqS[i][4];
    float v[16];
    #pragma unroll
    for (int e=0;e<16;++e) v[e] = 0.f;
    float s1 = 0.f;
    #pragma unroll 4
    for (int m=0;m<32;++m){
      const int c = m*5+f;
      float a = oq0*TH(0,c) + oq1*TH(1,c) + oq2*TH(2,c) + oq3*TH(3,c) + oq4*TH(4,c);
      a = eluf_p(a);
      s1 += fabsf(a);
      #pragma unroll
      for (int e=0;e<16;++e) v[e] += a*WINS(m,e);
    }
    const float inv = 1.f/(s1 + 1e-6f);
    #pragma unroll
    for (int e=0;e<16;++e) v[e] *= inv;
    float vv = 0.f;
    #pragma unroll
    for (int e=0;e<16;++e) vv += v[e]*v[e];
    float best = 3.4e38f; int bi = 0;
    #pragma unroll 4
    for (int c=0;c<32;++c){
      float d = 0.f;
      #pragma unroll
      for (int e=0;e<16;++e) d += v[e]*CBS(c,e);
      float d2 = vv - 2.f*d + CBN(c);
      if (d2 < best){ best = d2; bi = c; }
    }
    idxv[tid] = bi;
    sse = best;
  } else {
    for (int o = tid-160; o < 480; o += 96){
      int j = o/15, c = o%15;
      float a = 0.f;
      #pragma unroll
      for (int d=0;d<5;++d) a += sf[j][d]*w1g[d][c];
      xw[j][c] = a;
    }
    const float* wg = ga_wout + k*512;
    for (int o = tid-160; o < 1024; o += 96){
      int c = o >> 5, m = o & 31;
      float a = 0.f;
      #pragma unroll
      for (int e=0;e<16;++e) a += CBS(c,e)*wg[e*32+m];
      DECF(c,m) = a;
    }
  }
  __syncthreads();

  // ---- SE partial: s[f]*1024 = sum_i cb[idx[f,i]]·wsum
  {
    float sep = 0.f;
    if (tid < 160){
      const int id = idxv[tid];
      #pragma unroll
      for (int e=0;e<16;++e) sep += CBS(id,e)*WSUM(e);
    }
    #pragma unroll
    for (int off=16; off>=1; off>>=1) sep += __shfl_xor(sep, off);
    if (tid < 160 && (tid&31)==0) wredS[tid>>5] = sep;
  }
  __syncthreads();
  if (tid == 0){
    float h0=0.f, h1=0.f;
    #pragma unroll
    for (int f=0; f<5; ++f){
      float s = wredS[f] * (1.f/1024.f);
      h0 += s*sw1[f][0]; h1 += s*sw1[f][1];
    }
    h0 = fmaxf(h0,0.f); h1 = fmaxf(h1,0.f);
    #pragma unroll
    for (int f=0; f<5; ++f) gse[f] = sigm(h0*sw2[0][f] + h1*sw2[1][f]);
  }
  __syncthreads();

  // ---- combine: A[i][m] = elu( sum_f elu(dec[idx[f,i]][m]*(1+gse[f])) )
  for (int o = tid; o < 1024; o += 256){
    int i = o & 31, m = o >> 5;
    float a = 0.f;
    #pragma unroll
    for (int f=0; f<5; ++f)
      a += eluf_f(DECF(idxv[(f<<5)|i], m)*(1.f+gse[f]));
    adjFT[m][i] = eluf_f(a);
  }
  __syncthreads();
  if (tid < 32){
    float s = 0.f;
    #pragma unroll
    for (int m=0;m<32;++m) s += fabsf(adjFT[m][tid]);
    float inv = 1.f/(s + 1e-6f);
    #pragma unroll
    for (int m=0;m<32;++m) adjFT[m][tid] *= inv;
  }
  __syncthreads();

  // ---- res_gcn layer 1 (xw precomputed); x1c overlays dead th region
  float* x1c = X1C_BASE;   // [32][20]
  for (int o = tid; o < 480; o += 256){
    int i = o/15, c = o%15;
    float a = 0.f;
    for (int j=0;j<32;++j) a += adjFT[j][i]*xw[j][c];
    x1c[i*20 + 5+c] = seluf(a);
  }
  for (int o = tid; o < 160; o += 256) x1c[(o/5)*20 + o%5] = ((const float*)sf)[o];
  __syncthreads();
  cbam32(x1c, 20, &c1w1[0][0], &c1w2[0][0], c1cv,
         avgv, mxv, cav, smean, smax, sav, h1s, h2s, tid);

  // ---- res_gcn layer 2; cat2 overlays dead cbS/winS/dec region
  float* cat2 = CAT2_BASE; // [32][50]
  for (int o = tid; o < 960; o += 256){
    int j = o/30, c = o%30;
    float a = 0.f;
    #pragma unroll
    for (int d=0;d<20;++d) a += x1c[j*20+d]*w2g[d][c];
    xw[j][c] = a;
  }
  __syncthreads();
  for (int o = tid; o < 960; o += 256){
    int i = o/30, c = o%30;
    float a = 0.f;
    for (int j=0;j<32;++j) a += adjFT[j][i]*xw[j][c];
    cat2[i*50 + 20+c] = seluf(a);
  }
  for (int o = tid; o < 640; o += 256) cat2[(o/20)*50 + o%20] = x1c[o];
  __syncthreads();
  cbam32(cat2, 50, &c2w1[0][0], &c2w2[0][0], c2cv,
         avgv, mxv, cav, smean, smax, sav, h1s, h2s, tid);

  // ---- write xi = elu(out) to workspace, layout [b][k][32][50]
  {
    float* dst = xr + (size_t)(b*7 + k)*1600;
    for (int o = tid; o < 1600; o += 256) dst[o] = eluf_f(cat2[o]);
  }

  // ---- loss contribution
  {
    float p = sse;
    for (int off=32; off>=1; off>>=1) p += __shfl_down(p, off);
    if ((tid & 63) == 0) ssew[tid>>6] = p;
  }
  __syncthreads();
  if (tid == 0)
    atomicAdd(lossAcc, (ssew[0]+ssew[1]+ssew[2]+ssew[3]) * (1.25f/2621440.f));
}

// ---------------- Kernel 2: attention coarsening + coarse pipeline ----------
// R12 structure (512 threads) with R14 barrier reduction: SE chain and C=7
// CBAM chains are wave-0-local -> WSYNC. Last block emits loss. NO waves hint.
__global__ __launch_bounds__(512)
void k_attco(const float* __restrict__ xr, const float* __restrict__ Watt,
             const float* __restrict__ co_p, const float* __restrict__ co_bias,
             const float* __restrict__ co_q, const float* __restrict__ co_theta,
             const float* __restrict__ co_sew1, const float* __restrict__ co_sew2,
             const float* __restrict__ co_cb, const float* __restrict__ co_win, const float* __restrict__ co_wout,
             const float* __restrict__ co_w1, const float* __restrict__ co_w2,
             const float* __restrict__ cc1w1, const float* __restrict__ cc1w2, const float* __restrict__ cc1cv,
             const float* __restrict__ cc2w1, const float* __restrict__ cc2w2, const float* __restrict__ cc2cv,
             float* __restrict__ outp, float* __restrict__ lossAcc, int* __restrict__ doneCnt)
{
  const int b = blockIdx.x, tid = threadIdx.x;
  const int lane = tid & 63, wid = tid >> 6;   // wid in 0..7
  __shared__ float uB[2368];         // zeG[64][36]@0, vvG[64]@2304; x1/x2 overlay post-VQ
  __shared__ float xc[7][50];
  __shared__ float pm[7][7];
  __shared__ float o_[7][50];
  __shared__ float oqS[7][50];
  __shared__ float adjZ[50][7][7];   // later reused as recon[f][i][m]
  __shared__ float winS[7][32];
  __shared__ float woutS[32][7];
  __shared__ float cbS[128][33];     // padded codebook; att buffers overlay pre-stage
  __shared__ float decC[128][8];     // decC[c][m] = cb[c]·wout[:,m], padded
  __shared__ int   idxv[350];
  __shared__ float s_se[50], hh[25], gse[50];
  __shared__ float adjA[49];
  __shared__ float adjco[7][7];
  __shared__ float cw1a[7], cw2a[7], cva[14], cw1b[7], cw2b[7], cvb[14];
  __shared__ float avgv[7], mxv[7], cav[7], smean[60], smax[60], sav[60];
  __shared__ float hsum[1];
  __shared__ float ssew[8];

  // ---- att buffers alias the cbS region (dead until cbS staged) ----
  float* attU  = &cbS[0][0];
  float* M_    = attU;        // [7][50]
  float* S_    = attU + 350;  // [7][80]
  float* T_    = attU + 910;  // [7][50]
  float* attS_ = attU + 1260; // [7][32]
  float* aw_   = attU + 1484; // [7][32]

  // ---- stage small consts (none used by att phases) ----
  for (int i = tid; i < 49;   i += 512) ((float*)pm)[i]    = co_p[i];
  for (int i = tid; i < 224;  i += 512) ((float*)winS)[i]  = co_win[i];
  for (int i = tid; i < 224;  i += 512) ((float*)woutS)[i] = co_wout[i];
  if (tid < 7)                       cw1a[tid]     = cc1w1[tid];
  else if (tid >= 32 && tid < 39)    cw2a[tid-32]  = cc1w2[tid-32];
  else if (tid >= 64 && tid < 78)    cva[tid-64]   = cc1cv[tid-64];
  else if (tid >= 96 && tid < 103)   cw1b[tid-96]  = cc2w1[tid-96];
  else if (tid >= 128 && tid < 135)  cw2b[tid-128] = cc2w2[tid-128];
  else if (tid >= 160 && tid < 174)  cvb[tid-160]  = cc2cv[tid-160];

  // ======== attention coarsening (verbatim math; xr from global) ============
  const float* src = xr + (size_t)b*11200;
  for (int o = tid; o < 350; o += 512){
    int kk = o/50, d = o%50;
    float s = 0.f;
    const float* p = src + kk*1600 + d;
    for (int n=0;n<32;++n) s += p[n*50];
    M_[kk*50+d] = s;
  }
  __syncthreads();
  for (int o = tid; o < 560; o += 512){
    int kk = o/80, h = o%80;
    float s = 0.f;
    #pragma unroll 8
    for (int d=0;d<50;++d) s += M_[kk*50+d]*Watt[d*80+h];
    S_[kk*80+h] = s;
  }
  __syncthreads();
  for (int o = tid; o < 350; o += 512){
    int kk = o/50, d = o%50;
    float s = 0.f;
    const float* wr = Watt + d*80;
    #pragma unroll 8
    for (int h=0;h<80;++h) s += S_[kk*80+h]*wr[h];
    T_[kk*50+d] = s;
  }
  __syncthreads();
  for (int o = tid; o < 224; o += 512){
    int kk = o >> 5, n = o & 31;
    float s = 0.f;
    const float* p = src + kk*1600 + n*50;
    #pragma unroll 8
    for (int d=0;d<50;++d) s += p[d]*T_[kk*50+d];
    attS_[kk*32+n] = s;
  }
  __syncthreads();
  if (tid < 7){
    float m = -INFINITY;
    for (int n=0;n<32;++n) m = fmaxf(m, attS_[tid*32+n]);
    float s = 0.f;
    for (int n=0;n<32;++n){ float e = expf(attS_[tid*32+n]-m); aw_[tid*32+n] = e; s += e; }
    for (int n=0;n<32;++n) aw_[tid*32+n] = aw_[tid*32+n]/s;
  }
  __syncthreads();
  for (int o = tid; o < 350; o += 512){
    int kk = o/50, d = o%50;
    float s = 0.f;
    const float* p = src + kk*1600 + d;
    for (int n=0;n<32;++n) s += aw_[kk*32+n]*p[n*50];
    xc[kk][d] = s;
  }
  __syncthreads();   // att buffers now dead; cbS region reusable

  // ======== coarse pipeline ================================================
  // stage cbS + o_ = co_p @ xc + bias (same phase; independent)
  for (int i = tid; i < 4096; i += 512) cbS[i>>5][i&31] = co_cb[i];
  for (int o = tid; o < 350; o += 512){
    int i = o/50, d = o%50;
    float a = co_bias[o];
    #pragma unroll
    for (int j=0;j<7;++j) a += pm[i][j]*xc[j][d];
    o_[i][d] = a;
  }
  __syncthreads();
  // oq = o @ co_q (precise, pre-VQ)
  for (int o = tid; o < 350; o += 512){
    int i = o/50, e = o%50;
    float a = 0.f;
    #pragma unroll 8
    for (int d=0;d<50;++d) a += o_[i][d]*co_q[d*50+e];
    oqS[i][e] = a;
  }
  __syncthreads();
  // g = elu(oq @ co_theta) -> adjZ[f][i][n2]  (c = n2*50+f), precise
  for (int c = tid; c < 350; c += 512){
    float acc[7] = {0,0,0,0,0,0,0};
    #pragma unroll 5
    for (int e=0;e<50;++e){
      float t = co_theta[e*350+c];
      #pragma unroll
      for (int i=0;i<7;++i) acc[i] += oqS[i][e]*t;
    }
    int f = c % 50, n2 = c / 50;
    #pragma unroll
    for (int i=0;i<7;++i) adjZ[f][i][n2] = eluf_p(acc[i]);
  }
  __syncthreads();
  // L1 normalize each (f,i) row over n2 (precise)
  for (int o = tid; o < 350; o += 512){
    float* rowp = &adjZ[0][0][0] + o*7;
    float s = 0.f;
    #pragma unroll
    for (int m=0;m<7;++m) s += fabsf(rowp[m]);
    float den = s + 1e-6f;
    #pragma unroll
    for (int m=0;m<7;++m) rowp[m] /= den;
  }
  __syncthreads();

  // ---- VQ over 128 codes, dim 32: single pass, 2 codes/lane from LDS;
  //      8 waves -> 8 vectors/wave per 64-tile
  float c0[32], c1[32];
  #pragma unroll
  for (int e=0;e<32;++e){ c0[e] = cbS[lane][e]; c1[e] = cbS[lane+64][e]; }
  float cn0 = 0.f, cn1 = 0.f;
  #pragma unroll
  for (int e=0;e<32;++e){ cn0 += c0[e]*c0[e]; cn1 += c1[e]*c1[e]; }
  float* zeG = uB;            // [64][36], rows 16B-aligned
  float* vvG = uB + 2304;     // [64]
  float sse = 0.f;
  for (int g0 = 0; g0 < 350; g0 += 64){
    int nv = (350 - g0 < 64) ? (350 - g0) : 64;
    for (int o = tid; o < nv*32; o += 512){
      int v = o >> 5, e = o & 31;
      const float* rowp = &adjZ[0][0][0] + (g0+v)*7;
      float a = 0.f;
      #pragma unroll
      for (int m=0;m<7;++m) a += rowp[m]*winS[m][e];
      zeG[v*36+e] = a;
    }
    __syncthreads();
    if (tid < nv){
      float a = 0.f;
      #pragma unroll
      for (int e=0;e<32;++e){ float t = zeG[tid*36+e]; a += t*t; }
      vvG[tid] = a;
    }
    __syncthreads();
    for (int v = wid; v < nv; v += 8){
      float d0 = 0.f, d1 = 0.f;
      #pragma unroll
      for (int e=0;e<32;++e){
        float ve = zeG[v*36+e];
        d0 += ve*c0[e]; d1 += ve*c1[e];
      }
      float vv = vvG[v];
      float dist0 = vv - 2.f*d0 + cn0;
      float dist1 = vv - 2.f*d1 + cn1;
      float best = dist0; int bi = lane;
      if (dist1 < best){ best = dist1; bi = lane + 64; }
      for (int off = 32; off >= 1; off >>= 1){
        float ob = __shfl_xor(best, off);
        int oi   = __shfl_xor(bi, off);
        if (ob < best || (ob == best && oi < bi)){ best = ob; bi = oi; }
      }
      if (lane == 0){ idxv[g0+v] = bi; sse += best; }
    }
    __syncthreads();
  }

  // ---- decC table (from LDS cbS) then recon lookup into adjZ
  for (int o = tid; o < 896; o += 512){
    int c = o / 7, m = o % 7;
    float a = 0.f;
    #pragma unroll
    for (int e=0;e<32;++e) a += cbS[c][e]*woutS[e][m];
    decC[c][m] = a;
  }
  __syncthreads();
  for (int o = tid; o < 2450; o += 512){
    int fr = o / 49, r = o % 49, i = r / 7, m = r % 7;
    (&adjZ[0][0][0])[o] = decC[idxv[fr*7 + i]][m];
  }
  __syncthreads();
  const float* reconC = &adjZ[0][0][0];

  // ---- SE chain: all wave-0-local (tid<50/25/50/49/7) -> WSYNC only
  if (tid < 50){
    float s = 0.f;
    for (int r=0;r<49;++r) s += reconC[tid*49 + r];
    s_se[tid] = s / 49.f;
  }
  WSYNC();
  if (tid < 25){
    float a = 0.f;
    #pragma unroll 8
    for (int f=0;f<50;++f) a += s_se[f]*co_sew1[f*25+tid];
    hh[tid] = fmaxf(a, 0.f);
  }
  WSYNC();
  if (tid < 50){
    float a = 0.f;
    #pragma unroll 8
    for (int t2=0;t2<25;++t2) a += hh[t2]*co_sew2[t2*50+tid];
    gse[tid] = sigm(a);
  }
  WSYNC();
  if (tid < 49){
    float a = 0.f;
    for (int f=0;f<50;++f) a += eluf_f(reconC[f*49+tid]*(1.f+gse[f]));
    adjA[tid] = eluf_f(a);
  }
  WSYNC();
  if (tid < 7){
    float s = 0.f;
    #pragma unroll
    for (int m=0;m<7;++m) s += fabsf(adjA[tid*7+m]);
    float den = s + 1e-6f;
    #pragma unroll
    for (int m=0;m<7;++m) adjco[tid][m] = adjA[tid*7+m]/den;
  }
  __syncthreads();

  // ---- res_gcn2 layer 1 (buffers overlay dead zeG)
  float* x1w = uB;           // [7][55]
  float* x1s = uB + 385;
  float* x1b = uB + 770;
  float* xw2 = uB + 1155;    // [7][60]
  float* x2s = uB + 1575;
  for (int o = tid; o < 385; o += 512){
    int j = o/55, c = o%55;
    float a = 0.f;
    #pragma unroll 8
    for (int d=0;d<50;++d) a += xc[j][d]*co_w1[d*55+c];
    x1w[o] = a;
  }
  __syncthreads();
  for (int o = tid; o < 385; o += 512){
    int i = o/55, c = o%55;
    float a = 0.f;
    #pragma unroll
    for (int j=0;j<7;++j) a += adjco[i][j]*x1w[j*55+c];
    x1s[o] = seluf(a);
  }
  __syncthreads();
  // cbam (C=7, D=55): channel chain wave-0-local
  if (tid < 7){
    float s=0.f, m=-INFINITY;
    for (int d=0;d<55;++d){ float v = x1s[tid*55+d]; s += v; m = fmaxf(m,v); }
    avgv[tid] = s/55.f; mxv[tid] = m;
  }
  WSYNC();
  if (tid == 0){
    float ha=0.f, hm=0.f;
    #pragma unroll
    for (int c=0;c<7;++c){ ha += avgv[c]*cw1a[c]; hm += mxv[c]*cw1a[c]; }
    hsum[0] = fmaxf(ha,0.f) + fmaxf(hm,0.f);
  }
  WSYNC();
  if (tid < 7) cav[tid] = sigm(hsum[0]*cw2a[tid]);
  __syncthreads();
  for (int o = tid; o < 385; o += 512) x1w[o] = x1s[o]*cav[o/55];
  __syncthreads();
  if (tid < 55){
    float s=0.f, m=-INFINITY;
    #pragma unroll
    for (int c=0;c<7;++c){ float v = x1w[c*55+tid]; s += v; m = fmaxf(m,v); }
    smean[tid] = s/7.f; smax[tid] = m;
  }
  WSYNC();
  if (tid < 55){
    float a = 0.f;
    #pragma unroll
    for (int t2=0;t2<7;++t2){
      int dd = tid + t2 - 3;
      if (dd >= 0 && dd < 55) a += cva[t2]*smean[dd] + cva[7+t2]*smax[dd];
    }
    sav[tid] = a;
  }
  __syncthreads();
  for (int o = tid; o < 385; o += 512)
    x1b[o] = x1w[o]*sigm(sav[o%55]) + x1s[o];
  __syncthreads();

  // ---- res_gcn2 layer 2
  for (int o = tid; o < 420; o += 512){
    int j = o/60, c = o%60;
    float a = 0.f;
    #pragma unroll 8
    for (int d=0;d<55;++d) a += x1b[j*55+d]*co_w2[d*60+c];
    xw2[o] = a;
  }
  __syncthreads();
  for (int o = tid; o < 420; o += 512){
    int i = o/60, c = o%60;
    float a = 0.f;
    #pragma unroll
    for (int j=0;j<7;++j) a += adjco[i][j]*xw2[j*60+c];
    x2s[o] = seluf(a);
  }
  __syncthreads();
  // cbam (C=7, D=60): channel chain wave-0-local
  if (tid < 7){
    float s=0.f, m=-INFINITY;
    for (int d=0;d<60;++d){ float v = x2s[tid*60+d]; s += v; m = fmaxf(m,v); }
    avgv[tid] = s/60.f; mxv[tid] = m;
  }
  WSYNC();
  if (tid == 0){
    float ha=0.f, hm=0.f;
    #pragma unroll
    for (int c=0;c<7;++c){ ha += avgv[c]*cw1b[c]; hm += mxv[c]*cw1b[c]; }
    hsum[0] = fmaxf(ha,0.f) + fmaxf(hm,0.f);
  }
  WSYNC();
  if (tid < 7) cav[tid] = sigm(hsum[0]*cw2b[tid]);
  __syncthreads();
  for (int o = tid; o < 420; o += 512) xw2[o] = x2s[o]*cav[o/60];
  __syncthreads();
  if (tid < 60){
    float s=0.f, m=-INFINITY;
    #pragma unroll
    for (int c=0;c<7;++c){ float v = xw2[c*60+tid]; s += v; m = fmaxf(m,v); }
    smean[tid] = s/7.f; smax[tid] = m;
  }
  WSYNC();
  if (tid < 60){
    float a = 0.f;
    #pragma unroll
    for (int t2=0;t2<7;++t2){
      int dd = tid + t2 - 3;
      if (dd >= 0 && dd < 60) a += cvb[t2]*smean[dd] + cvb[7+t2]*smax[dd];
    }
    sav[tid] = a;
  }
  __syncthreads();
  for (int o = tid; o < 420; o += 512){
    float val = xw2[o]*sigm(sav[o%60]) + x2s[o];
    outp[1 + (size_t)b*420 + o] = val;
  }

  // ---- loss contribution; last-finishing block emits outp[0]
  if (lane == 0) ssew[wid] = sse;
  __syncthreads();
  if (tid == 0){
    float t = 0.f;
    #pragma unroll
    for (int w2_ = 0; w2_ < 8; ++w2_) t += ssew[w2_];
    atomicAdd(lossAcc, t * (2.5f/11468800.f));
    __threadfence();                          // publish the add device-wide
    int prev = atomicAdd(doneCnt, 1);
    if (prev == (int)gridDim.x - 1){
      outp[0] = atomicAdd(lossAcc, 0.0f);     // atomic read: coherent final sum
    }
  }
}

extern "C" void kernel_launch(void* const* d_in, const int* in_sizes, int n_in,
                              void* d_out, int out_size, void* d_ws, size_t ws_size,
                              hipStream_t stream)
{
  const float* x          = (const float*)d_in[0];
  const float* ga_p       = (const float*)d_in[1];
  const float* ga_bias    = (const float*)d_in[2];
  const float* ga_q       = (const float*)d_in[3];
  const float* ga_theta   = (const float*)d_in[4];
  const float* ga_se_w1   = (const float*)d_in[5];
  const float* ga_se_w2   = (const float*)d_in[6];
  const float* ga_cb      = (const float*)d_in[7];
  const float* ga_win     = (const float*)d_in[8];
  const float* ga_wout    = (const float*)d_in[9];
  const float* rg_w1      = (const float*)d_in[10];
  const float* rg_w2      = (const float*)d_in[11];
  const float* cb1_w1     = (const float*)d_in[12];
  const float* cb1_w2     = (const float*)d_in[13];
  const float* cb1_conv   = (const float*)d_in[14];
  const float* cb2_w1     = (const float*)d_in[15];
  const float* cb2_w2     = (const float*)d_in[16];
  const float* cb2_conv   = (const float*)d_in[17];
  const float* co_p       = (const float*)d_in[18];
  const float* co_bias    = (const float*)d_in[19];
  const float* co_q       = (const float*)d_in[20];
  const float* co_theta   = (const float*)d_in[21];
  const float* co_se_w1   = (const float*)d_in[22];
  const float* co_se_w2   = (const float*)d_in[23];
  const float* co_cb      = (const float*)d_in[24];
  const float* co_win     = (const float*)d_in[25];
  const float* co_wout    = (const float*)d_in[26];
  const float* co_rg_w1   = (const float*)d_in[27];
  const float* co_rg_w2   = (const float*)d_in[28];
  const float* co_cb1_w1  = (const float*)d_in[29];
  const float* co_cb1_w2  = (const float*)d_in[30];
  const float* co_cb1_cv  = (const float*)d_in[31];
  const float* co_cb2_w1  = (const float*)d_in[32];
  const float* co_cb2_w2  = (const float*)d_in[33];
  const float* co_cb2_cv  = (const float*)d_in[34];
  const float* W_att      = (const float*)d_in[35];

  char* base = (char*)d_ws;
  float* lossAcc = (float*)base;                 // 4B @0 (zeroed below)
  int*   doneCnt = (int*)(base + 64);            // 4B @64 (zeroed below)
  float* xr  = (float*)(base + 256);             // [1024][7][32][50] f32

  float* outp = (float*)d_out;

  hipMemsetAsync(d_ws, 0, 256, stream);
  k_fine<<<7168, 256, 0, stream>>>(x, ga_p, ga_bias, ga_q, ga_theta, ga_se_w1, ga_se_w2,
                                   ga_cb, ga_win, ga_wout, rg_w1, rg_w2,
                                   cb1_w1, cb1_w2, cb1_conv, cb2_w1, cb2_w2, cb2_conv,
                                   xr, lossAcc);
  k_attco<<<1024, 512, 0, stream>>>(xr, W_att, co_p, co_bias, co_q, co_theta,
                                    co_se_w1, co_se_w2, co_cb, co_win, co_wout,
                                    co_rg_w1, co_rg_w2,
                                    co_cb1_w1, co_cb1_w2, co_cb1_cv,
                                    co_cb2_w1, co_cb2_w2, co_cb2_cv,
                                    outp, lossAcc, doneCnt);
}